// Round 4
// baseline (53.130 us; speedup 1.0000x reference)
//
#include <hip/hip_runtime.h>
#include <hip/hip_bf16.h>

// ToroidalEmbedding:
//   idx:   (B,T)=(4,4096) int32      -> 16384 tokens
//   rho:   (50257, 1536) fp32
//   theta: (50257, 1536) fp32
//   gain:  (512, 2) fp32
//   out:   (B,T, 512*4) fp32 = (16384, 2048)
//
// Per token t, per block b (0..511):
//   r0..r2 = rho[idx[t], b*3 .. b*3+2]
//   t0..t2 = theta[idx[t], b*3 .. b*3+2]
//   s2 = sin(t2); c0,c1,c2 = cos(t0..t2)
//   sig0 = r0
//   sig1 = sig0 * (gain[b][0]*s2) + r1
//   sig2 = sig1 * (gain[b][1]*s2) + r2
//   out[t, b*4 .. b*4+3] = { sig0*c0, sig1*c1, sig2*c2, sig2*s2 }
//
// R4: 4 tokens per workgroup. All idx values scalar-loaded up front, all
// 24 row-loads issued before any compute (4x deeper MLP per wave), gain
// loaded once per thread. NT stores kept (R3: -5%, preserves L3 residency
// of rho/theta rows for duplicate tokens).

#define N_BLOCKS 512
#define RANK 3
#define PPT (N_BLOCKS * RANK)        // 1536
#define OUT_PER_TOKEN (N_BLOCKS * 4) // 2048
#define TOKENS_PER_WG 4

typedef float f32x4 __attribute__((ext_vector_type(4)));

__global__ __launch_bounds__(N_BLOCKS) void toroidal_embed_kernel(
    const int* __restrict__ idx,
    const float* __restrict__ rho,
    const float* __restrict__ theta,
    const float* __restrict__ gain,
    float* __restrict__ out,
    int n_tokens)
{
    const int tok0 = blockIdx.x * TOKENS_PER_WG;
    const int b = threadIdx.x;                 // toroid-block index 0..511

    // per-thread gain, loaded once (same for all tokens)
    const float g0 = gain[b * 2 + 0];
    const float g1 = gain[b * 2 + 1];

    // scalar (wave-uniform) idx loads for all 4 tokens up front
    size_t row[TOKENS_PER_WG];
#pragma unroll
    for (int k = 0; k < TOKENS_PER_WG; ++k)
        row[k] = (size_t)idx[tok0 + k];

    // issue ALL row loads before any compute: 4 tokens x (rho3 + theta3)
    float r0[TOKENS_PER_WG], r1[TOKENS_PER_WG], r2[TOKENS_PER_WG];
    float t0[TOKENS_PER_WG], t1[TOKENS_PER_WG], t2[TOKENS_PER_WG];
#pragma unroll
    for (int k = 0; k < TOKENS_PER_WG; ++k) {
        const float* __restrict__ rp = rho   + row[k] * PPT + (size_t)b * RANK;
        const float* __restrict__ tp = theta + row[k] * PPT + (size_t)b * RANK;
        r0[k] = rp[0]; r1[k] = rp[1]; r2[k] = rp[2];
        t0[k] = tp[0]; t1[k] = tp[1]; t2[k] = tp[2];
    }

#pragma unroll
    for (int k = 0; k < TOKENS_PER_WG; ++k) {
        const float s2 = __sinf(t2[k]);
        const float c0 = __cosf(t0[k]);
        const float c1 = __cosf(t1[k]);
        const float c2 = __cosf(t2[k]);

        const float sig0 = r0[k];
        const float sig1 = fmaf(sig0, g0 * s2, r1[k]);
        const float sig2 = fmaf(sig1, g1 * s2, r2[k]);

        f32x4 o;
        o.x = sig0 * c0;
        o.y = sig1 * c1;
        o.z = sig2 * c2;
        o.w = sig2 * s2;

        __builtin_nontemporal_store(
            o, reinterpret_cast<f32x4*>(out + (size_t)(tok0 + k) * OUT_PER_TOKEN
                                            + (size_t)b * 4));
    }
}

extern "C" void kernel_launch(void* const* d_in, const int* in_sizes, int n_in,
                              void* d_out, int out_size, void* d_ws, size_t ws_size,
                              hipStream_t stream)
{
    const int*   idx   = (const int*)d_in[0];
    const float* rho   = (const float*)d_in[1];
    const float* theta = (const float*)d_in[2];
    const float* gain  = (const float*)d_in[3];
    float*       out   = (float*)d_out;

    const int n_tokens = in_sizes[0];          // B*T = 16384 (divisible by 4)

    dim3 grid(n_tokens / TOKENS_PER_WG);
    dim3 block(N_BLOCKS);
    toroidal_embed_kernel<<<grid, block, 0, stream>>>(idx, rho, theta, gain, out, n_tokens);
}